// Round 3
// baseline (155.397 us; speedup 1.0000x reference)
//
#include <hip/hip_runtime.h>
#include <hip/hip_bf16.h>

#define B_ 4
#define N_ 16384
#define K_ 16
#define NEG 0.2f
#define EPSBN 1e-5f
#define INV_SIG2 2500.0f

typedef unsigned short u16;
typedef unsigned int   u32;
typedef __attribute__((ext_vector_type(8))) short short8;
typedef __attribute__((ext_vector_type(4))) float f32x4;

__device__ __forceinline__ float bf2f(u16 h){
  return __uint_as_float(((u32)h) << 16);
}
__device__ __forceinline__ u16 f2bf(float f){
  u32 x = __float_as_uint(f);
  x += 0x7fffu + ((x >> 16) & 1u);
  return (u16)(x >> 16);
}

// ---------------- K0: wconv [o][c][j] fp32 -> wbf [j][o][c] bf16 ----------------
__global__ void k0_wprep(const float* __restrict__ wconv, u16* __restrict__ wbf){
  const int idx = blockIdx.x * 256 + threadIdx.x;
  if (idx < 9*128*64){
    const int j = idx >> 13;
    const int rem = idx & 8191;
    const int o = rem >> 6, c = rem & 63;
    wbf[idx] = f2bf(wconv[(o*64 + c)*9 + j]);
  }
}

// ---------------- K1: u = (W1-W2)^T x, v = W2^T x, stored [B][N][64] bf16 --------
__global__ __launch_bounds__(256) void k1_uv(const float* __restrict__ x,
                                             const float* __restrict__ we,
                                             u16* __restrict__ uo,
                                             u16* __restrict__ vo){
  const int n0 = blockIdx.x * 128;
  const int b  = blockIdx.y;
  __shared__ u16   Wl[64*128];   // [c'][r] bf16, r<64 -> WA=W1-W2, r>=64 -> WB=W2
  __shared__ float Xl[64*128];   // [c'][n]
  const int tid = threadIdx.x;
  for (int idx = tid; idx < 64*128; idx += 256){
    const int cp = idx >> 7, r = idx & 127;
    float w;
    if (r < 64) w = we[r*128 + cp] - we[r*128 + 64 + cp];
    else        w = we[(r-64)*128 + 64 + cp];
    Wl[cp*128 + r] = f2bf(w);
  }
  for (int idx = tid; idx < 64*128; idx += 256){
    const int cp = idx >> 7, nl = idx & 127;
    Xl[cp*128 + nl] = x[(b*64 + cp)*N_ + n0 + nl];
  }
  __syncthreads();
  const int tr = tid & 15, tc = tid >> 4;
  float acc[8][8];
  #pragma unroll
  for (int i=0;i<8;++i)
    #pragma unroll
    for (int j=0;j<8;++j) acc[i][j] = 0.f;
  for (int cp=0; cp<64; ++cp){
    const uint4 wv = *(const uint4*)&Wl[cp*128 + tr*8];
    float wr[8];
    wr[0]=__uint_as_float(wv.x<<16); wr[1]=__uint_as_float(wv.x & 0xffff0000u);
    wr[2]=__uint_as_float(wv.y<<16); wr[3]=__uint_as_float(wv.y & 0xffff0000u);
    wr[4]=__uint_as_float(wv.z<<16); wr[5]=__uint_as_float(wv.z & 0xffff0000u);
    wr[6]=__uint_as_float(wv.w<<16); wr[7]=__uint_as_float(wv.w & 0xffff0000u);
    const float4 x0 = *(const float4*)&Xl[cp*128 + tc*8];
    const float4 x1 = *(const float4*)&Xl[cp*128 + tc*8 + 4];
    const float xr[8] = {x0.x,x0.y,x0.z,x0.w,x1.x,x1.y,x1.z,x1.w};
    #pragma unroll
    for (int i=0;i<8;++i)
      #pragma unroll
      for (int j=0;j<8;++j)
        acc[i][j] = fmaf(wr[i], xr[j], acc[i][j]);
  }
  u16* dst = (tr < 8) ? uo : vo;
  const int cb = (tr & 7) * 8;
  #pragma unroll
  for (int ni=0; ni<8; ++ni){
    const int n = n0 + tc*8 + ni;
    u32 p0 = (u32)f2bf(acc[0][ni]) | ((u32)f2bf(acc[1][ni]) << 16);
    u32 p1 = (u32)f2bf(acc[2][ni]) | ((u32)f2bf(acc[3][ni]) << 16);
    u32 p2 = (u32)f2bf(acc[4][ni]) | ((u32)f2bf(acc[5][ni]) << 16);
    u32 p3 = (u32)f2bf(acc[6][ni]) | ((u32)f2bf(acc[7][ni]) << 16);
    *(uint4*)&dst[(b*N_ + n)*64 + cb] = make_uint4(p0,p1,p2,p3);
  }
}

// ---------------- K2 v2: gather h = u[i]+v[j]; per-(b,n) max/min over k; stats ----
// 2048 blocks x 256 thr. XCD-pinned batches: b = (bid&7)>>1 so each XCD touches
// only one batch's u/v (~4.2MB ~ L2). lane = (g=k-slot group)<<4 | (q=ch-quad).
// Each lane loads dwordx2 (4 channels); 8 loads per point.
__global__ __launch_bounds__(256) void k2_gather(const u16* __restrict__ uo,
                                                 const u16* __restrict__ vo,
                                                 const int* __restrict__ eidx,
                                                 u16* __restrict__ wmaxo,
                                                 u16* __restrict__ wmino,
                                                 float* __restrict__ stats){
  const int bid = blockIdx.x;
  const int xcd = bid & 7;
  const int b   = xcd >> 1;
  const int n0  = ((bid >> 3) + (xcd & 1)*256) * 32;
  const int tid = threadIdx.x;
  const int wid = tid >> 6, lane = tid & 63;
  const int g = lane >> 4, q = lane & 15;
  const u16* ub = uo + (size_t)b*N_*64;
  const u16* vb = vo + (size_t)b*N_*64;
  float ssum[4] = {0.f,0.f,0.f,0.f}, ssq[4] = {0.f,0.f,0.f,0.f};
  __shared__ float redS[4][64], redQ[4][64];

  for (int i = 0; i < 8; ++i){
    const int n = n0 + wid*8 + i;
    int raw = 0;
    if (lane < 32)
      raw = eidx[(lane >> 4)*(B_*N_*K_) + (b*N_ + n)*K_ + (lane & 15)];
    // lanes 0..15: j (neighbor, eidx[0]); lanes 16..31: i (center, eidx[1])
    float h[4][4];   // [ks][ch]
    #pragma unroll
    for (int ks = 0; ks < 4; ++ks){
      const int k = ks*4 + g;
      const int jj = __shfl(raw, k);
      const int ii = __shfl(raw, 16 + k);
      const uint2 uu = *(const uint2*)&ub[ii*64 + q*4];
      const uint2 vv = *(const uint2*)&vb[jj*64 + q*4];
      h[ks][0] = __uint_as_float(uu.x << 16)          + __uint_as_float(vv.x << 16);
      h[ks][1] = __uint_as_float(uu.x & 0xffff0000u)  + __uint_as_float(vv.x & 0xffff0000u);
      h[ks][2] = __uint_as_float(uu.y << 16)          + __uint_as_float(vv.y << 16);
      h[ks][3] = __uint_as_float(uu.y & 0xffff0000u)  + __uint_as_float(vv.y & 0xffff0000u);
    }
    float mxr[4], mnr[4];
    #pragma unroll
    for (int c = 0; c < 4; ++c){
      float mx = fmaxf(fmaxf(h[0][c], h[1][c]), fmaxf(h[2][c], h[3][c]));
      float mn = fminf(fminf(h[0][c], h[1][c]), fminf(h[2][c], h[3][c]));
      ssum[c] += (h[0][c] + h[1][c]) + (h[2][c] + h[3][c]);
      ssq[c] = fmaf(h[0][c], h[0][c], fmaf(h[1][c], h[1][c],
               fmaf(h[2][c], h[2][c], fmaf(h[3][c], h[3][c], ssq[c]))));
      mx = fmaxf(mx, __shfl_xor(mx, 16));
      mx = fmaxf(mx, __shfl_xor(mx, 32));
      mn = fminf(mn, __shfl_xor(mn, 16));
      mn = fminf(mn, __shfl_xor(mn, 32));
      mxr[c] = mx; mnr[c] = mn;
    }
    if (g == 0){
      u32 p0 = (u32)f2bf(mxr[0]) | ((u32)f2bf(mxr[1]) << 16);
      u32 p1 = (u32)f2bf(mxr[2]) | ((u32)f2bf(mxr[3]) << 16);
      *(uint2*)&wmaxo[((size_t)(b*N_ + n))*64 + q*4] = make_uint2(p0, p1);
      u32 q0 = (u32)f2bf(mnr[0]) | ((u32)f2bf(mnr[1]) << 16);
      u32 q1 = (u32)f2bf(mnr[2]) | ((u32)f2bf(mnr[3]) << 16);
      *(uint2*)&wmino[((size_t)(b*N_ + n))*64 + q*4] = make_uint2(q0, q1);
    }
  }

  // block reduction of per-channel stats
  #pragma unroll
  for (int c = 0; c < 4; ++c){
    ssum[c] += __shfl_xor(ssum[c], 16);
    ssum[c] += __shfl_xor(ssum[c], 32);
    ssq[c]  += __shfl_xor(ssq[c], 16);
    ssq[c]  += __shfl_xor(ssq[c], 32);
  }
  if (g == 0){
    #pragma unroll
    for (int c = 0; c < 4; ++c){
      redS[wid][q*4 + c] = ssum[c];
      redQ[wid][q*4 + c] = ssq[c];
    }
  }
  __syncthreads();
  if (tid < 64){
    atomicAdd(&stats[tid], redS[0][tid] + redS[1][tid] + redS[2][tid] + redS[3][tid]);
  } else if (tid < 128){
    const int c = tid - 64;
    atomicAdd(&stats[64 + c], redQ[0][c] + redQ[1][c] + redQ[2][c] + redQ[3][c]);
  }
}

// ---------------- K3: finalize BN affine: sct[c]=scale, sct[64+c]=shift ----------
__global__ void k3_finalize(const float* __restrict__ stats,
                            const float* __restrict__ gamma,
                            const float* __restrict__ beta,
                            float* __restrict__ sct){
  const int c = threadIdx.x;
  const float inv = 1.0f / (float)(B_*N_*K_);
  const float mean = stats[c] * inv;
  const float var  = stats[64+c] * inv - mean*mean;
  const float s = gamma[c] * rsqrtf(var + EPSBN);
  sct[c] = s;
  sct[64+c] = beta[c] - mean*s;
}

// ---------------- K4: MFMA weighted conv ------------------------------------------
// grid (N/64, B), block 256 (4 waves). Wave w: o in [w*32, w*32+32), n-tile 64.
// out[o][n] = sum_j wgt[j][n] * (Wj x hbn_shift_j)[o][n] + bias
__global__ __launch_bounds__(256) void k4_mfma(const u16* __restrict__ wmaxo,
                                               const u16* __restrict__ wmino,
                                               const float* __restrict__ sct,
                                               const float* __restrict__ coords,
                                               const u16* __restrict__ wbf,
                                               const float* __restrict__ bconv,
                                               float* __restrict__ out){
  const int n0 = blockIdx.x * 64;
  const int b  = blockIdx.y;
  const int tid = threadIdx.x;
  const int w = tid >> 6, lane = tid & 63;
  const int r15 = lane & 15, kg = lane >> 4;

  __shared__ u16 hl[72*72];     // [m_local][c], row stride 72 (pad) -> 10.4 KB
  __shared__ float wgt[9*64];   // [j][n] Gaussian weights

  // --- build hbn tile: h = leaky(s*max_or_min + t), rows m = n0-4 .. n0+67
  {
    const int c = tid & 63;
    const float s = sct[c], t = sct[64+c];
    const u16* src = ((s >= 0.f) ? wmaxo : wmino) + (size_t)b*N_*64 + c;
    #pragma unroll
    for (int it = 0; it < 18; ++it){
      const int ml = (tid >> 6) + it*4;
      const int m = n0 - 4 + ml;
      float hv = 0.f;
      if (m >= 0 && m < N_){
        hv = fmaf(s, bf2f(src[(size_t)m*64]), t);
        hv = (hv >= 0.f) ? hv : NEG*hv;
      }
      hl[ml*72 + c] = f2bf(hv);
    }
  }
  // --- build Gaussian weights wgt[j][n]
  for (int idx = tid; idx < 576; idx += 256){
    const int j = idx >> 6, n = idx & 63;
    const int mc = n0 + n, mt = mc + j - 4;
    float wv = 0.f;
    if (mt >= 0 && mt < N_){
      float d2 = 0.f;
      #pragma unroll
      for (int d = 0; d < 3; ++d){
        const float dd = coords[(b*3+d)*N_ + mt] - coords[(b*3+d)*N_ + mc];
        d2 = fmaf(dd, dd, d2);
      }
      wv = __expf(-INV_SIG2 * d2);
    }
    wgt[idx] = wv;
  }
  __syncthreads();

  // --- MFMA main loop over taps j
  const u16* abase = wbf + ((w*32 + r15)*64 + kg*8);   // + j*8192 + of*1024 + cc
  const u16* hbase = &hl[r15*72 + kg*8];               // + (nf*16 + j)*72 + cc
  f32x4 acc[2][4] = {};
  const f32x4 zero = {0.f, 0.f, 0.f, 0.f};

  for (int j = 0; j < 9; ++j){
    float wj[4];
    #pragma unroll
    for (int nf = 0; nf < 4; ++nf) wj[nf] = wgt[j*64 + nf*16 + r15];
    short8 bfr[4][2];
    #pragma unroll
    for (int nf = 0; nf < 4; ++nf){
      bfr[nf][0] = *(const short8*)&hbase[(nf*16 + j)*72];
      bfr[nf][1] = *(const short8*)&hbase[(nf*16 + j)*72 + 32];
    }
    #pragma unroll
    for (int of = 0; of < 2; ++of){
      const short8 a0 = *(const short8*)&abase[j*8192 + of*1024];
      const short8 a1 = *(const short8*)&abase[j*8192 + of*1024 + 32];
      #pragma unroll
      for (int nf = 0; nf < 4; ++nf){
        f32x4 p = __builtin_amdgcn_mfma_f32_16x16x32_bf16(a0, bfr[nf][0], zero, 0, 0, 0);
        p = __builtin_amdgcn_mfma_f32_16x16x32_bf16(a1, bfr[nf][1], p, 0, 0, 0);
        #pragma unroll
        for (int r = 0; r < 4; ++r)
          acc[of][nf][r] = fmaf(wj[nf], p[r], acc[of][nf][r]);
      }
    }
  }

  // --- epilogue: D layout col = lane&15, row = (lane>>4)*4 + reg
  #pragma unroll
  for (int of = 0; of < 2; ++of){
    #pragma unroll
    for (int r = 0; r < 4; ++r){
      const int o = w*32 + of*16 + kg*4 + r;
      const float bs = bconv[o];
      float* dst = &out[(size_t)(b*128 + o)*N_ + n0 + r15];
      #pragma unroll
      for (int nf = 0; nf < 4; ++nf)
        dst[nf*16] = acc[of][nf][r] + bs;
    }
  }
}

extern "C" void kernel_launch(void* const* d_in, const int* in_sizes, int n_in,
                              void* d_out, int out_size, void* d_ws, size_t ws_size,
                              hipStream_t stream){
  const float* x      = (const float*)d_in[0];
  const float* coords = (const float*)d_in[1];
  const int*   eidx   = (const int*)  d_in[2];
  const float* we     = (const float*)d_in[3];
  const float* gamma  = (const float*)d_in[4];
  const float* beta   = (const float*)d_in[5];
  const float* wconv  = (const float*)d_in[6];
  const float* bconv  = (const float*)d_in[7];
  float* out = (float*)d_out;
  char* ws = (char*)d_ws;
  // ws layout (bytes): u[8.39MB] v[8.39MB] wmax[8.39MB] wmin[8.39MB] stats[512] sct[512] wbf[147KB]
  u16* u     = (u16*)(ws);
  u16* v     = (u16*)(ws + 8388608);
  u16* wmax_ = (u16*)(ws + 16777216);
  u16* wmin_ = (u16*)(ws + 25165824);
  float* stats = (float*)(ws + 33554432);
  float* sct   = (float*)(ws + 33554944);
  u16* wbf     = (u16*)(ws + 33555456);

  hipMemsetAsync(stats, 0, 512, stream);
  k0_wprep<<<288, 256, 0, stream>>>(wconv, wbf);
  k1_uv<<<dim3(N_/128, B_), 256, 0, stream>>>(x, we, u, v);
  k2_gather<<<2048, 256, 0, stream>>>(u, v, eidx, wmax_, wmin_, stats);
  k3_finalize<<<1, 64, 0, stream>>>(stats, gamma, beta, sct);
  k4_mfma<<<dim3(N_/64, B_), 256, 0, stream>>>(wmax_, wmin_, sct, coords, wbf, bconv, out);
}